// Round 16
// baseline (165.610 us; speedup 1.0000x reference)
//
#include <hip/hip_runtime.h>
#include <math.h>

// Problem constants
#define B_  4
#define T_  2048
#define H_  1024
#define NH_ 16
#define HD_ 64

typedef __bf16  bf16x8  __attribute__((ext_vector_type(8)));
typedef float   f32x4   __attribute__((ext_vector_type(4)));
typedef unsigned short ushort8v __attribute__((ext_vector_type(8)));
typedef short   short4v __attribute__((ext_vector_type(4)));

__device__ __forceinline__ unsigned short f2bf(float f) {
    unsigned int u = __builtin_bit_cast(unsigned int, f);
    u += 0x7fffu + ((u >> 16) & 1u);
    return (unsigned short)(u >> 16);
}

// 16x16x16 bf16 MFMA (K=16): A/B k=(lane>>4)*4+j
__device__ __forceinline__ f32x4 mfma16x16x16bf16(short4v a, short4v b, f32x4 c) {
#if __has_builtin(__builtin_amdgcn_mfma_f32_16x16x16bf16_1k)
    return __builtin_amdgcn_mfma_f32_16x16x16bf16_1k(a, b, c, 0, 0, 0);
#else
    f32x4 d = c;
    asm volatile("v_mfma_f32_16x16x16_bf16 %0, %1, %2, %0\n\ts_nop 7\n\ts_nop 7"
                 : "+v"(d) : "v"(a), "v"(b));
    return d;
#endif
}

// global -> LDS direct DMA, 16B per lane (dest = wave-uniform base + lane*16)
__device__ __forceinline__ void gload_lds16(const unsigned short* g,
                                            unsigned short* l) {
    __builtin_amdgcn_global_load_lds(
        (const __attribute__((address_space(1))) unsigned int*)g,
        (__attribute__((address_space(3))) unsigned int*)l, 16, 0, 0);
}

// ---------------------------------------------------------------------------
__global__ void cvt_f32_bf16(const float* __restrict__ in,
                             unsigned short* __restrict__ out, int n8) {
    int stride = gridDim.x * blockDim.x;
    for (int i = blockIdx.x * blockDim.x + threadIdx.x; i < n8; i += stride) {
        const float4* p = reinterpret_cast<const float4*>(in) + (size_t)i * 2;
        float4 f0 = p[0], f1 = p[1];
        ushort8v o;
        o[0] = f2bf(f0.x); o[1] = f2bf(f0.y); o[2] = f2bf(f0.z); o[3] = f2bf(f0.w);
        o[4] = f2bf(f1.x); o[5] = f2bf(f1.y); o[6] = f2bf(f1.z); o[7] = f2bf(f1.w);
        reinterpret_cast<ushort8v*>(out)[i] = o;
    }
}

// three weight matrices in one launch (grid.y selects)
__global__ void cvt_w3(const float* __restrict__ Wq, const float* __restrict__ Wk,
                       const float* __restrict__ Wv,
                       unsigned short* __restrict__ oq, unsigned short* __restrict__ ok,
                       unsigned short* __restrict__ ov, int n8) {
    const int z = blockIdx.y;
    const float* in = (z == 0) ? Wq : (z == 1) ? Wk : Wv;
    unsigned short* out = (z == 0) ? oq : (z == 1) ? ok : ov;
    int stride = gridDim.x * blockDim.x;
    for (int i = blockIdx.x * blockDim.x + threadIdx.x; i < n8; i += stride) {
        const float4* p = reinterpret_cast<const float4*>(in) + (size_t)i * 2;
        float4 f0 = p[0], f1 = p[1];
        ushort8v o;
        o[0] = f2bf(f0.x); o[1] = f2bf(f0.y); o[2] = f2bf(f0.z); o[3] = f2bf(f0.w);
        o[4] = f2bf(f1.x); o[5] = f2bf(f1.y); o[6] = f2bf(f1.z); o[7] = f2bf(f1.w);
        reinterpret_cast<ushort8v*>(out)[i] = o;
    }
}

// ---------------------------------------------------------------------------
// QKV projection GEMM, all three in one launch (blockIdx.z selects).
// Staging: global_load_lds width=16 into LINEAR [128][64] LDS with XOR
// swizzle (rule 21: inverse-swizzled SOURCE + swizzled READ, linear dest).
//   source col16' = (lane&7) ^ (row&7);  read col16 = (ks*4+hi) ^ (lo&7)
// z=0: Q -> out[bh][t][d] row-major
// z=1: K -> fragment order Kf[bh][kt][ct][ks][flane][8]
// z=2: V -> fragment order Vf[bh][kt][ct][flane][dt][4]
__global__ __launch_bounds__(256) void qkv_gemm_all(
    const unsigned short* __restrict__ X,
    const unsigned short* __restrict__ Wq,
    const unsigned short* __restrict__ Wk,
    const unsigned short* __restrict__ Wv,
    const float* __restrict__ bq,
    const float* __restrict__ bk,
    const float* __restrict__ bv,
    unsigned short* __restrict__ Qo,
    unsigned short* __restrict__ Ko,
    unsigned short* __restrict__ Vo)
{
    const int z = blockIdx.z;
    const unsigned short* W = (z == 0) ? Wq : (z == 1) ? Wk : Wv;
    const float* bias = (z == 0) ? bq : (z == 1) ? bk : bv;
    unsigned short* out = (z == 0) ? Qo : (z == 1) ? Ko : Vo;

    const int K = 1024;
    const int t    = threadIdx.x;
    const int lane = t & 63;
    const int wid  = t >> 6;
    const int lo = lane & 15, hi = lane >> 4;
    const int wm = wid >> 1, wn = wid & 1;
    const int m0 = blockIdx.y * 128;
    const int n0 = blockIdx.x * 128;

    __shared__ unsigned short As[128 * 64];
    __shared__ unsigned short Bs[128 * 64];

    // per-lane staging geometry (constant across k0)
    const int srowoff = lane >> 3;              // 0..7 within an 8-row group
    const int scol    = lane & 7;               // lds 16B slot

    f32x4 acc[4][4];
#pragma unroll
    for (int i = 0; i < 4; ++i)
#pragma unroll
        for (int j = 0; j < 4; ++j) acc[i][j] = (f32x4){0.f, 0.f, 0.f, 0.f};

    for (int k0 = 0; k0 < K; k0 += 64) {
        __syncthreads();
#pragma unroll
        for (int p = 0; p < 4; ++p) {
            const int rowb = p * 32 + wid * 8;          // wave-uniform
            const int row  = rowb + srowoff;
            const int c16  = scol ^ (row & 7);          // inverse-swizzled src
            gload_lds16(&X[(size_t)(m0 + row) * K + k0 + c16 * 8], &As[rowb * 64]);
            gload_lds16(&W[(size_t)(n0 + row) * K + k0 + c16 * 8], &Bs[rowb * 64]);
        }
        __syncthreads();
#pragma unroll
        for (int ks = 0; ks < 2; ++ks) {
            bf16x8 a[4], b[4];
#pragma unroll
            for (int mt = 0; mt < 4; ++mt) {
                const int row = wm * 64 + mt * 16 + lo;
                a[mt] = *reinterpret_cast<const bf16x8*>(
                    &As[row * 64 + (((ks * 4 + hi) ^ (lo & 7)) * 8)]);
            }
#pragma unroll
            for (int nt = 0; nt < 4; ++nt) {
                const int row = wn * 64 + nt * 16 + lo;
                b[nt] = *reinterpret_cast<const bf16x8*>(
                    &Bs[row * 64 + (((ks * 4 + hi) ^ (lo & 7)) * 8)]);
            }
#pragma unroll
            for (int mt = 0; mt < 4; ++mt)
#pragma unroll
                for (int nt = 0; nt < 4; ++nt)
                    acc[mt][nt] = __builtin_amdgcn_mfma_f32_16x16x32_bf16(
                        a[mt], b[nt], acc[mt][nt], 0, 0, 0);
        }
    }

#pragma unroll
    for (int nt = 0; nt < 4; ++nt) {
        int n = n0 + wn * 64 + nt * 16 + lo;
        float bv_ = bias[n];
        int h = n >> 6, d = n & 63;
#pragma unroll
        for (int mt = 0; mt < 4; ++mt) {
            int mbase = m0 + wm * 64 + mt * 16 + hi * 4;
            int bb = mbase >> 11;
            int tt = mbase & 2047;
            size_t tilebase = ((size_t)(bb * NH_ + h) * 32 + (tt >> 6)) * 4096;
            if (z == 2) {
                // V fragments: tilebase + ct*1024 + flane*16 + dt*4 (+j)
                ushort4 pk;
                pk.x = f2bf(acc[mt][nt][0] + bv_);
                pk.y = f2bf(acc[mt][nt][1] + bv_);
                pk.z = f2bf(acc[mt][nt][2] + bv_);
                pk.w = f2bf(acc[mt][nt][3] + bv_);
                *reinterpret_cast<ushort4*>(
                    &out[tilebase + (size_t)mt * 1024 + (size_t)(hi * 16 + lo) * 16 + nt * 4]) = pk;
            } else if (z == 1) {
                // K fragments: 4 scalar stores (lo_f = hi*4 + r)
                const int ksd = d >> 5;
                const int hif = (d >> 3) & 3;
                const int jd  = d & 7;
                size_t fragbase = tilebase + (size_t)(mt * 2 + ksd) * 512;
#pragma unroll
                for (int r = 0; r < 4; ++r)
                    out[fragbase + (size_t)(hif * 16 + hi * 4 + r) * 8 + jd] =
                        f2bf(acc[mt][nt][r] + bv_);
            } else {
                size_t base = (size_t)(bb * NH_ + h) * T_;
#pragma unroll
                for (int r = 0; r < 4; ++r)
                    out[(base + tt + r) * HD_ + d] = f2bf(acc[mt][nt][r] + bv_);
            }
        }
    }
}

// ---------------------------------------------------------------------------
// Causal flash attention v15 (unchanged from R15): static-exp softmax,
// fragment-order K/V, 4096 blocks, 2-wave kv-split, addition merge.
__global__ __launch_bounds__(128, 2) void attn_fwd15(
    const unsigned short* __restrict__ Q,
    const unsigned short* __restrict__ Kf,
    const unsigned short* __restrict__ Vf,
    const float* __restrict__ amask,
    float* __restrict__ out)
{
    const float SC    = 0.125f * 1.44269504089f;
    const float LOG2E = 1.44269504089f;

    const int lane = threadIdx.x & 63;
    const int w    = threadIdx.x >> 6;          // 0..1
    const int lo = lane & 15, hi = lane >> 4;

    const int bid    = blockIdx.x;
    const int xcd    = bid & 7;
    const int within = bid >> 3;                // 0..511
    const int bh     = xcd * 8 + (within & 7);
    const int u      = 63 - (within >> 3);      // 63..0
    const int b      = bh >> 4;
    const int h      = bh & 15;

    const unsigned short* Qg = Q + (size_t)bh * T_ * HD_;
    const float* am = amask + (size_t)b * T_;
    float* outBase = out + (size_t)b * T_ * H_ + h * HD_;

    __shared__ f32x4 Lo[2][4][64];
    __shared__ float Ll[2][64];

    const int q0   = u * 32;
    const int nt   = (u >> 1) + 1;
    const int half = nt >> 1;
    const int ktBeg = w ? half : 0;
    const int ktEnd = w ? nt : half;

    bf16x8 qf[2][2];
#pragma unroll
    for (int mt = 0; mt < 2; ++mt)
#pragma unroll
        for (int ks = 0; ks < 2; ++ks)
            qf[mt][ks] = *reinterpret_cast<const bf16x8*>(
                &Qg[(size_t)(q0 + mt * 16 + lo) * HD_ + ks * 32 + hi * 8]);

    f32x4 o[2][4];
#pragma unroll
    for (int mt = 0; mt < 2; ++mt)
#pragma unroll
        for (int dt = 0; dt < 4; ++dt) o[mt][dt] = (f32x4){0.f, 0.f, 0.f, 0.f};
    float l_r[2] = {0.f, 0.f};

    const unsigned short* kp = Kf + ((size_t)bh * 32 + ktBeg) * 4096;
    const unsigned short* vp = Vf + ((size_t)bh * 32 + ktBeg) * 4096;
    const float*          ap = am + ktBeg * 64;

    for (int kt = ktBeg; kt < ktEnd; ++kt, kp += 4096, vp += 4096, ap += 64) {
        const int kv0 = kt * 64;

        bf16x8 kf[4][2];
#pragma unroll
        for (int ct = 0; ct < 4; ++ct)
#pragma unroll
            for (int ks = 0; ks < 2; ++ks)
                kf[ct][ks] = *reinterpret_cast<const bf16x8*>(
                    &kp[(ct * 2 + ks) * 512 + lane * 8]);

        short4v vf[4][4];
#pragma unroll
        for (int ct = 0; ct < 4; ++ct) {
            union { ushort8v u8; short4v s4[2]; } va, vb;
            va.u8 = *reinterpret_cast<const ushort8v*>(&vp[ct * 1024 + lane * 16]);
            vb.u8 = *reinterpret_cast<const ushort8v*>(&vp[ct * 1024 + lane * 16 + 8]);
            vf[0][ct] = va.s4[0];
            vf[1][ct] = va.s4[1];
            vf[2][ct] = vb.s4[0];
            vf[3][ct] = vb.s4[1];
        }

        f32x4 amv[4];
#pragma unroll
        for (int ct = 0; ct < 4; ++ct)
            amv[ct] = *reinterpret_cast<const f32x4*>(&ap[ct * 16 + hi * 4]) * LOG2E;

        f32x4 s[2][4];
#pragma unroll
        for (int mt = 0; mt < 2; ++mt)
#pragma unroll
            for (int ct = 0; ct < 4; ++ct) s[mt][ct] = (f32x4){0.f, 0.f, 0.f, 0.f};
#pragma unroll
        for (int ks = 0; ks < 2; ++ks)
#pragma unroll
            for (int ct = 0; ct < 4; ++ct)
#pragma unroll
                for (int mt = 0; mt < 2; ++mt)
                    s[mt][ct] = __builtin_amdgcn_mfma_f32_16x16x32_bf16(
                        kf[ct][ks], qf[mt][ks], s[mt][ct], 0, 0, 0);

        const bool edge = (kv0 + 63 > q0);

        short4v p[2][4];
#pragma unroll
        for (int mt = 0; mt < 2; ++mt) {
            f32x4 rsv = (f32x4){0.f, 0.f, 0.f, 0.f};
#pragma unroll
            for (int ct = 0; ct < 4; ++ct) {
                f32x4 sv;
#pragma unroll
                for (int r = 0; r < 4; ++r)
                    sv[r] = fmaf(s[mt][ct][r], SC, amv[ct][r]);
                if (edge) {
                    const int q = q0 + mt * 16 + lo;
#pragma unroll
                    for (int r = 0; r < 4; ++r)
                        if (kv0 + ct * 16 + hi * 4 + r > q) sv[r] = -INFINITY;
                }
                short4v pk;
#pragma unroll
                for (int r = 0; r < 4; ++r) {
                    float pe = exp2f(sv[r]);      // static exponent
                    rsv[r] += pe;
                    __bf16 hb = (__bf16)pe;
                    pk[r] = __builtin_bit_cast(short, hb);
                }
                p[mt][ct] = pk;
            }
            l_r[mt] += (rsv[0] + rsv[1]) + (rsv[2] + rsv[3]);
        }

#pragma unroll
        for (int ct = 0; ct < 4; ++ct)
#pragma unroll
            for (int mt = 0; mt < 2; ++mt)
#pragma unroll
                for (int dt = 0; dt < 4; ++dt)
                    o[mt][dt] = mfma16x16x16bf16(vf[dt][ct], p[mt][ct], o[mt][dt]);
    }

    if (w == 1) {
#pragma unroll
        for (int mt = 0; mt < 2; ++mt) {
            Ll[mt][lane] = l_r[mt];
#pragma unroll
            for (int dt = 0; dt < 4; ++dt)
                Lo[mt][dt][lane] = o[mt][dt];
        }
    }
    __syncthreads();
    if (w == 0) {
#pragma unroll
        for (int mt = 0; mt < 2; ++mt) {
            float lf = l_r[mt] + Ll[mt][lane];
            lf += __shfl_xor(lf, 16, 64);
            lf += __shfl_xor(lf, 32, 64);
            const float inv = 1.0f / lf;
            const int tq = q0 + mt * 16 + lo;
            float* orow = outBase + (size_t)tq * H_;
#pragma unroll
            for (int dt = 0; dt < 4; ++dt) {
                f32x4 v = (o[mt][dt] + Lo[mt][dt][lane]) * inv;
                *reinterpret_cast<f32x4*>(&orow[dt * 16 + hi * 4]) = v;
            }
        }
    }
}

// ---------------------------------------------------------------------------
extern "C" void kernel_launch(void* const* d_in, const int* in_sizes, int n_in,
                              void* d_out, int out_size, void* d_ws, size_t ws_size,
                              hipStream_t stream) {
    const float* hs    = (const float*)d_in[0];
    const float* amask = (const float*)d_in[1];
    const float* Wq    = (const float*)d_in[2];
    const float* bq    = (const float*)d_in[3];
    const float* Wk    = (const float*)d_in[4];
    const float* bk    = (const float*)d_in[5];
    const float* Wv    = (const float*)d_in[6];
    const float* bv    = (const float*)d_in[7];
    float* out = (float*)d_out;

    unsigned short* Xbf = (unsigned short*)d_ws;
    unsigned short* Wqb = Xbf + (size_t)8192 * 1024;
    unsigned short* Wkb = Wqb + (size_t)1024 * 1024;
    unsigned short* Wvb = Wkb + (size_t)1024 * 1024;
    unsigned short* Qb  = Wvb + (size_t)1024 * 1024;
    unsigned short* Kfb = Qb  + (size_t)B_ * NH_ * T_ * HD_;   // K fragment order
    unsigned short* Vfb = Kfb + (size_t)B_ * NH_ * T_ * HD_;   // V fragment order

    cvt_f32_bf16<<<4096, 256, 0, stream>>>(hs, Xbf, (8192 * 1024) / 8);
    dim3 gw(512, 3);
    cvt_w3<<<gw, 256, 0, stream>>>(Wq, Wk, Wv, Wqb, Wkb, Wvb, (1024 * 1024) / 8);

    dim3 g(8, 64, 3);
    qkv_gemm_all<<<g, 256, 0, stream>>>(Xbf, Wqb, Wkb, Wvb, bq, bk, bv,
                                        Qb, Kfb, Vfb);

    attn_fwd15<<<4096, 128, 0, stream>>>(Qb, Kfb, Vfb, amask, out);
}

// Round 17
// 156.825 us; speedup vs baseline: 1.0560x; 1.0560x over previous
//
#include <hip/hip_runtime.h>
#include <math.h>

// Problem constants
#define B_  4
#define T_  2048
#define H_  1024
#define NH_ 16
#define HD_ 64

typedef __bf16  bf16x8  __attribute__((ext_vector_type(8)));
typedef float   f32x4   __attribute__((ext_vector_type(4)));
typedef unsigned short ushort8v __attribute__((ext_vector_type(8)));
typedef short   short4v __attribute__((ext_vector_type(4)));

__device__ __forceinline__ unsigned short f2bf(float f) {
    unsigned int u = __builtin_bit_cast(unsigned int, f);
    u += 0x7fffu + ((u >> 16) & 1u);
    return (unsigned short)(u >> 16);
}

// 16x16x16 bf16 MFMA (K=16): A/B k=(lane>>4)*4+j
__device__ __forceinline__ f32x4 mfma16x16x16bf16(short4v a, short4v b, f32x4 c) {
#if __has_builtin(__builtin_amdgcn_mfma_f32_16x16x16bf16_1k)
    return __builtin_amdgcn_mfma_f32_16x16x16bf16_1k(a, b, c, 0, 0, 0);
#else
    f32x4 d = c;
    asm volatile("v_mfma_f32_16x16x16_bf16 %0, %1, %2, %0\n\ts_nop 7\n\ts_nop 7"
                 : "+v"(d) : "v"(a), "v"(b));
    return d;
#endif
}

// global -> LDS direct DMA, 16B per lane (dest = wave-uniform base + lane*16)
__device__ __forceinline__ void gload_lds16(const unsigned short* g,
                                            unsigned short* l) {
    __builtin_amdgcn_global_load_lds(
        (const __attribute__((address_space(1))) unsigned int*)g,
        (__attribute__((address_space(3))) unsigned int*)l, 16, 0, 0);
}

// ---------------------------------------------------------------------------
__global__ void cvt_f32_bf16(const float* __restrict__ in,
                             unsigned short* __restrict__ out, int n8) {
    int stride = gridDim.x * blockDim.x;
    for (int i = blockIdx.x * blockDim.x + threadIdx.x; i < n8; i += stride) {
        const float4* p = reinterpret_cast<const float4*>(in) + (size_t)i * 2;
        float4 f0 = p[0], f1 = p[1];
        ushort8v o;
        o[0] = f2bf(f0.x); o[1] = f2bf(f0.y); o[2] = f2bf(f0.z); o[3] = f2bf(f0.w);
        o[4] = f2bf(f1.x); o[5] = f2bf(f1.y); o[6] = f2bf(f1.z); o[7] = f2bf(f1.w);
        reinterpret_cast<ushort8v*>(out)[i] = o;
    }
}

// three weight matrices in one launch (grid.y selects)
__global__ void cvt_w3(const float* __restrict__ Wq, const float* __restrict__ Wk,
                       const float* __restrict__ Wv,
                       unsigned short* __restrict__ oq, unsigned short* __restrict__ ok,
                       unsigned short* __restrict__ ov, int n8) {
    const int z = blockIdx.y;
    const float* in = (z == 0) ? Wq : (z == 1) ? Wk : Wv;
    unsigned short* out = (z == 0) ? oq : (z == 1) ? ok : ov;
    int stride = gridDim.x * blockDim.x;
    for (int i = blockIdx.x * blockDim.x + threadIdx.x; i < n8; i += stride) {
        const float4* p = reinterpret_cast<const float4*>(in) + (size_t)i * 2;
        float4 f0 = p[0], f1 = p[1];
        ushort8v o;
        o[0] = f2bf(f0.x); o[1] = f2bf(f0.y); o[2] = f2bf(f0.z); o[3] = f2bf(f0.w);
        o[4] = f2bf(f1.x); o[5] = f2bf(f1.y); o[6] = f2bf(f1.z); o[7] = f2bf(f1.w);
        reinterpret_cast<ushort8v*>(out)[i] = o;
    }
}

// ---------------------------------------------------------------------------
// QKV projection GEMM, one 1D launch with XCD-locality decode:
//   xcd = id&7; within = id>>3; z = within/64; rest = within%64;
//   x(n-block) = rest>>3; y(m-block) = xcd*8 + (rest&7)
// Each XCD owns 8 X m-panels (2MB) and walks z-major: per-phase working set
// (8 X panels + one W = 4MB) fits its L2 -> X fetched ~once, W once per z.
// Staging: global_load_lds w16, linear LDS, XOR swizzle (src+read, rule 21).
__global__ __launch_bounds__(256) void qkv_gemm_all(
    const unsigned short* __restrict__ X,
    const unsigned short* __restrict__ Wq,
    const unsigned short* __restrict__ Wk,
    const unsigned short* __restrict__ Wv,
    const float* __restrict__ bq,
    const float* __restrict__ bk,
    const float* __restrict__ bv,
    unsigned short* __restrict__ Qo,
    unsigned short* __restrict__ Ko,
    unsigned short* __restrict__ Vo)
{
    const int id     = blockIdx.x;          // 0..1535
    const int xcd    = id & 7;
    const int within = id >> 3;             // 0..191
    const int z      = within >> 6;         // 0..2
    const int rest   = within & 63;
    const int xb     = rest >> 3;           // n-block 0..7
    const int yb     = xcd * 8 + (rest & 7);// m-block 0..63

    const unsigned short* W = (z == 0) ? Wq : (z == 1) ? Wk : Wv;
    const float* bias = (z == 0) ? bq : (z == 1) ? bk : bv;
    unsigned short* out = (z == 0) ? Qo : (z == 1) ? Ko : Vo;

    const int K = 1024;
    const int t    = threadIdx.x;
    const int lane = t & 63;
    const int wid  = t >> 6;
    const int lo = lane & 15, hi = lane >> 4;
    const int wm = wid >> 1, wn = wid & 1;
    const int m0 = yb * 128;
    const int n0 = xb * 128;

    __shared__ unsigned short As[128 * 64];
    __shared__ unsigned short Bs[128 * 64];

    const int srowoff = lane >> 3;              // 0..7 within an 8-row group
    const int scol    = lane & 7;               // lds 16B slot

    f32x4 acc[4][4];
#pragma unroll
    for (int i = 0; i < 4; ++i)
#pragma unroll
        for (int j = 0; j < 4; ++j) acc[i][j] = (f32x4){0.f, 0.f, 0.f, 0.f};

    for (int k0 = 0; k0 < K; k0 += 64) {
        __syncthreads();
#pragma unroll
        for (int p = 0; p < 4; ++p) {
            const int rowb = p * 32 + wid * 8;          // wave-uniform
            const int row  = rowb + srowoff;
            const int c16  = scol ^ (row & 7);          // inverse-swizzled src
            gload_lds16(&X[(size_t)(m0 + row) * K + k0 + c16 * 8], &As[rowb * 64]);
            gload_lds16(&W[(size_t)(n0 + row) * K + k0 + c16 * 8], &Bs[rowb * 64]);
        }
        __syncthreads();
#pragma unroll
        for (int ks = 0; ks < 2; ++ks) {
            bf16x8 a[4], b[4];
#pragma unroll
            for (int mt = 0; mt < 4; ++mt) {
                const int row = wm * 64 + mt * 16 + lo;
                a[mt] = *reinterpret_cast<const bf16x8*>(
                    &As[row * 64 + (((ks * 4 + hi) ^ (lo & 7)) * 8)]);
            }
#pragma unroll
            for (int nt = 0; nt < 4; ++nt) {
                const int row = wn * 64 + nt * 16 + lo;
                b[nt] = *reinterpret_cast<const bf16x8*>(
                    &Bs[row * 64 + (((ks * 4 + hi) ^ (lo & 7)) * 8)]);
            }
#pragma unroll
            for (int mt = 0; mt < 4; ++mt)
#pragma unroll
                for (int nt = 0; nt < 4; ++nt)
                    acc[mt][nt] = __builtin_amdgcn_mfma_f32_16x16x32_bf16(
                        a[mt], b[nt], acc[mt][nt], 0, 0, 0);
        }
    }

#pragma unroll
    for (int nt = 0; nt < 4; ++nt) {
        int n = n0 + wn * 64 + nt * 16 + lo;
        float bv_ = bias[n];
        int h = n >> 6, d = n & 63;
#pragma unroll
        for (int mt = 0; mt < 4; ++mt) {
            int mbase = m0 + wm * 64 + mt * 16 + hi * 4;
            int bb = mbase >> 11;
            int tt = mbase & 2047;
            size_t tilebase = ((size_t)(bb * NH_ + h) * 32 + (tt >> 6)) * 4096;
            if (z == 2) {
                // V fragments: tilebase + ct*1024 + flane*16 + dt*4 (+j)
                ushort4 pk;
                pk.x = f2bf(acc[mt][nt][0] + bv_);
                pk.y = f2bf(acc[mt][nt][1] + bv_);
                pk.z = f2bf(acc[mt][nt][2] + bv_);
                pk.w = f2bf(acc[mt][nt][3] + bv_);
                *reinterpret_cast<ushort4*>(
                    &out[tilebase + (size_t)mt * 1024 + (size_t)(hi * 16 + lo) * 16 + nt * 4]) = pk;
            } else if (z == 1) {
                // K fragments: 4 scalar stores (lo_f = hi*4 + r)
                const int ksd = d >> 5;
                const int hif = (d >> 3) & 3;
                const int jd  = d & 7;
                size_t fragbase = tilebase + (size_t)(mt * 2 + ksd) * 512;
#pragma unroll
                for (int r = 0; r < 4; ++r)
                    out[fragbase + (size_t)(hif * 16 + hi * 4 + r) * 8 + jd] =
                        f2bf(acc[mt][nt][r] + bv_);
            } else {
                size_t base = (size_t)(bb * NH_ + h) * T_;
#pragma unroll
                for (int r = 0; r < 4; ++r)
                    out[(base + tt + r) * HD_ + d] = f2bf(acc[mt][nt][r] + bv_);
            }
        }
    }
}

// ---------------------------------------------------------------------------
// Causal flash attention (unchanged from R15): static-exp softmax,
// fragment-order K/V, 4096 blocks, 2-wave kv-split, addition merge.
__global__ __launch_bounds__(128, 2) void attn_fwd15(
    const unsigned short* __restrict__ Q,
    const unsigned short* __restrict__ Kf,
    const unsigned short* __restrict__ Vf,
    const float* __restrict__ amask,
    float* __restrict__ out)
{
    const float SC    = 0.125f * 1.44269504089f;
    const float LOG2E = 1.44269504089f;

    const int lane = threadIdx.x & 63;
    const int w    = threadIdx.x >> 6;          // 0..1
    const int lo = lane & 15, hi = lane >> 4;

    const int bid    = blockIdx.x;
    const int xcd    = bid & 7;
    const int within = bid >> 3;                // 0..511
    const int bh     = xcd * 8 + (within & 7);
    const int u      = 63 - (within >> 3);      // 63..0
    const int b      = bh >> 4;
    const int h      = bh & 15;

    const unsigned short* Qg = Q + (size_t)bh * T_ * HD_;
    const float* am = amask + (size_t)b * T_;
    float* outBase = out + (size_t)b * T_ * H_ + h * HD_;

    __shared__ f32x4 Lo[2][4][64];
    __shared__ float Ll[2][64];

    const int q0   = u * 32;
    const int nt   = (u >> 1) + 1;
    const int half = nt >> 1;
    const int ktBeg = w ? half : 0;
    const int ktEnd = w ? nt : half;

    bf16x8 qf[2][2];
#pragma unroll
    for (int mt = 0; mt < 2; ++mt)
#pragma unroll
        for (int ks = 0; ks < 2; ++ks)
            qf[mt][ks] = *reinterpret_cast<const bf16x8*>(
                &Qg[(size_t)(q0 + mt * 16 + lo) * HD_ + ks * 32 + hi * 8]);

    f32x4 o[2][4];
#pragma unroll
    for (int mt = 0; mt < 2; ++mt)
#pragma unroll
        for (int dt = 0; dt < 4; ++dt) o[mt][dt] = (f32x4){0.f, 0.f, 0.f, 0.f};
    float l_r[2] = {0.f, 0.f};

    const unsigned short* kp = Kf + ((size_t)bh * 32 + ktBeg) * 4096;
    const unsigned short* vp = Vf + ((size_t)bh * 32 + ktBeg) * 4096;
    const float*          ap = am + ktBeg * 64;

    for (int kt = ktBeg; kt < ktEnd; ++kt, kp += 4096, vp += 4096, ap += 64) {
        const int kv0 = kt * 64;

        bf16x8 kf[4][2];
#pragma unroll
        for (int ct = 0; ct < 4; ++ct)
#pragma unroll
            for (int ks = 0; ks < 2; ++ks)
                kf[ct][ks] = *reinterpret_cast<const bf16x8*>(
                    &kp[(ct * 2 + ks) * 512 + lane * 8]);

        short4v vf[4][4];
#pragma unroll
        for (int ct = 0; ct < 4; ++ct) {
            union { ushort8v u8; short4v s4[2]; } va, vb;
            va.u8 = *reinterpret_cast<const ushort8v*>(&vp[ct * 1024 + lane * 16]);
            vb.u8 = *reinterpret_cast<const ushort8v*>(&vp[ct * 1024 + lane * 16 + 8]);
            vf[0][ct] = va.s4[0];
            vf[1][ct] = va.s4[1];
            vf[2][ct] = vb.s4[0];
            vf[3][ct] = vb.s4[1];
        }

        f32x4 amv[4];
#pragma unroll
        for (int ct = 0; ct < 4; ++ct)
            amv[ct] = *reinterpret_cast<const f32x4*>(&ap[ct * 16 + hi * 4]) * LOG2E;

        f32x4 s[2][4];
#pragma unroll
        for (int mt = 0; mt < 2; ++mt)
#pragma unroll
            for (int ct = 0; ct < 4; ++ct) s[mt][ct] = (f32x4){0.f, 0.f, 0.f, 0.f};
#pragma unroll
        for (int ks = 0; ks < 2; ++ks)
#pragma unroll
            for (int ct = 0; ct < 4; ++ct)
#pragma unroll
                for (int mt = 0; mt < 2; ++mt)
                    s[mt][ct] = __builtin_amdgcn_mfma_f32_16x16x32_bf16(
                        kf[ct][ks], qf[mt][ks], s[mt][ct], 0, 0, 0);

        const bool edge = (kv0 + 63 > q0);

        short4v p[2][4];
#pragma unroll
        for (int mt = 0; mt < 2; ++mt) {
            f32x4 rsv = (f32x4){0.f, 0.f, 0.f, 0.f};
#pragma unroll
            for (int ct = 0; ct < 4; ++ct) {
                f32x4 sv;
#pragma unroll
                for (int r = 0; r < 4; ++r)
                    sv[r] = fmaf(s[mt][ct][r], SC, amv[ct][r]);
                if (edge) {
                    const int q = q0 + mt * 16 + lo;
#pragma unroll
                    for (int r = 0; r < 4; ++r)
                        if (kv0 + ct * 16 + hi * 4 + r > q) sv[r] = -INFINITY;
                }
                short4v pk;
#pragma unroll
                for (int r = 0; r < 4; ++r) {
                    float pe = exp2f(sv[r]);      // static exponent
                    rsv[r] += pe;
                    __bf16 hb = (__bf16)pe;
                    pk[r] = __builtin_bit_cast(short, hb);
                }
                p[mt][ct] = pk;
            }
            l_r[mt] += (rsv[0] + rsv[1]) + (rsv[2] + rsv[3]);
        }

#pragma unroll
        for (int ct = 0; ct < 4; ++ct)
#pragma unroll
            for (int mt = 0; mt < 2; ++mt)
#pragma unroll
                for (int dt = 0; dt < 4; ++dt)
                    o[mt][dt] = mfma16x16x16bf16(vf[dt][ct], p[mt][ct], o[mt][dt]);
    }

    if (w == 1) {
#pragma unroll
        for (int mt = 0; mt < 2; ++mt) {
            Ll[mt][lane] = l_r[mt];
#pragma unroll
            for (int dt = 0; dt < 4; ++dt)
                Lo[mt][dt][lane] = o[mt][dt];
        }
    }
    __syncthreads();
    if (w == 0) {
#pragma unroll
        for (int mt = 0; mt < 2; ++mt) {
            float lf = l_r[mt] + Ll[mt][lane];
            lf += __shfl_xor(lf, 16, 64);
            lf += __shfl_xor(lf, 32, 64);
            const float inv = 1.0f / lf;
            const int tq = q0 + mt * 16 + lo;
            float* orow = outBase + (size_t)tq * H_;
#pragma unroll
            for (int dt = 0; dt < 4; ++dt) {
                f32x4 v = (o[mt][dt] + Lo[mt][dt][lane]) * inv;
                *reinterpret_cast<f32x4*>(&orow[dt * 16 + hi * 4]) = v;
            }
        }
    }
}

// ---------------------------------------------------------------------------
extern "C" void kernel_launch(void* const* d_in, const int* in_sizes, int n_in,
                              void* d_out, int out_size, void* d_ws, size_t ws_size,
                              hipStream_t stream) {
    const float* hs    = (const float*)d_in[0];
    const float* amask = (const float*)d_in[1];
    const float* Wq    = (const float*)d_in[2];
    const float* bq    = (const float*)d_in[3];
    const float* Wk    = (const float*)d_in[4];
    const float* bk    = (const float*)d_in[5];
    const float* Wv    = (const float*)d_in[6];
    const float* bv    = (const float*)d_in[7];
    float* out = (float*)d_out;

    unsigned short* Xbf = (unsigned short*)d_ws;
    unsigned short* Wqb = Xbf + (size_t)8192 * 1024;
    unsigned short* Wkb = Wqb + (size_t)1024 * 1024;
    unsigned short* Wvb = Wkb + (size_t)1024 * 1024;
    unsigned short* Qb  = Wvb + (size_t)1024 * 1024;
    unsigned short* Kfb = Qb  + (size_t)B_ * NH_ * T_ * HD_;   // K fragment order
    unsigned short* Vfb = Kfb + (size_t)B_ * NH_ * T_ * HD_;   // V fragment order

    cvt_f32_bf16<<<4096, 256, 0, stream>>>(hs, Xbf, (8192 * 1024) / 8);
    dim3 gw(512, 3);
    cvt_w3<<<gw, 256, 0, stream>>>(Wq, Wk, Wv, Wqb, Wkb, Wvb, (1024 * 1024) / 8);

    qkv_gemm_all<<<1536, 256, 0, stream>>>(Xbf, Wqb, Wkb, Wvb, bq, bk, bv,
                                           Qb, Kfb, Vfb);

    attn_fwd15<<<4096, 128, 0, stream>>>(Qb, Kfb, Vfb, amask, out);
}

// Round 18
// 154.302 us; speedup vs baseline: 1.0733x; 1.0164x over previous
//
#include <hip/hip_runtime.h>
#include <math.h>

// Problem constants
#define B_  4
#define T_  2048
#define H_  1024
#define NH_ 16
#define HD_ 64

typedef __bf16  bf16x8  __attribute__((ext_vector_type(8)));
typedef float   f32x4   __attribute__((ext_vector_type(4)));
typedef unsigned short ushort8v __attribute__((ext_vector_type(8)));
typedef short   short4v __attribute__((ext_vector_type(4)));

__device__ __forceinline__ unsigned short f2bf(float f) {
    unsigned int u = __builtin_bit_cast(unsigned int, f);
    u += 0x7fffu + ((u >> 16) & 1u);
    return (unsigned short)(u >> 16);
}

// 16x16x16 bf16 MFMA (K=16): A/B k=(lane>>4)*4+j
__device__ __forceinline__ f32x4 mfma16x16x16bf16(short4v a, short4v b, f32x4 c) {
#if __has_builtin(__builtin_amdgcn_mfma_f32_16x16x16bf16_1k)
    return __builtin_amdgcn_mfma_f32_16x16x16bf16_1k(a, b, c, 0, 0, 0);
#else
    f32x4 d = c;
    asm volatile("v_mfma_f32_16x16x16_bf16 %0, %1, %2, %0\n\ts_nop 7\n\ts_nop 7"
                 : "+v"(d) : "v"(a), "v"(b));
    return d;
#endif
}

// global -> LDS direct DMA, 16B per lane (dest = wave-uniform base + lane*16)
__device__ __forceinline__ void gload_lds16(const unsigned short* g,
                                            unsigned short* l) {
    __builtin_amdgcn_global_load_lds(
        (const __attribute__((address_space(1))) unsigned int*)g,
        (__attribute__((address_space(3))) unsigned int*)l, 16, 0, 0);
}

// ---------------------------------------------------------------------------
__global__ void cvt_f32_bf16(const float* __restrict__ in,
                             unsigned short* __restrict__ out, int n8) {
    int stride = gridDim.x * blockDim.x;
    for (int i = blockIdx.x * blockDim.x + threadIdx.x; i < n8; i += stride) {
        const float4* p = reinterpret_cast<const float4*>(in) + (size_t)i * 2;
        float4 f0 = p[0], f1 = p[1];
        ushort8v o;
        o[0] = f2bf(f0.x); o[1] = f2bf(f0.y); o[2] = f2bf(f0.z); o[3] = f2bf(f0.w);
        o[4] = f2bf(f1.x); o[5] = f2bf(f1.y); o[6] = f2bf(f1.z); o[7] = f2bf(f1.w);
        reinterpret_cast<ushort8v*>(out)[i] = o;
    }
}

// three weight matrices in one launch (grid.y selects)
__global__ void cvt_w3(const float* __restrict__ Wq, const float* __restrict__ Wk,
                       const float* __restrict__ Wv,
                       unsigned short* __restrict__ oq, unsigned short* __restrict__ ok,
                       unsigned short* __restrict__ ov, int n8) {
    const int z = blockIdx.y;
    const float* in = (z == 0) ? Wq : (z == 1) ? Wk : Wv;
    unsigned short* out = (z == 0) ? oq : (z == 1) ? ok : ov;
    int stride = gridDim.x * blockDim.x;
    for (int i = blockIdx.x * blockDim.x + threadIdx.x; i < n8; i += stride) {
        const float4* p = reinterpret_cast<const float4*>(in) + (size_t)i * 2;
        float4 f0 = p[0], f1 = p[1];
        ushort8v o;
        o[0] = f2bf(f0.x); o[1] = f2bf(f0.y); o[2] = f2bf(f0.z); o[3] = f2bf(f0.w);
        o[4] = f2bf(f1.x); o[5] = f2bf(f1.y); o[6] = f2bf(f1.z); o[7] = f2bf(f1.w);
        reinterpret_cast<ushort8v*>(out)[i] = o;
    }
}

// ---------------------------------------------------------------------------
// QKV projection GEMM: XCD-locality decode (R17) + 2-phase double-buffered
// prefetch (T3 minimal): stage(k+1) issued BEFORE compute(k); one
// __syncthreads (implicit vmcnt drain) per K-step -> L2 latency hides under
// MFMA. Unrolled by 2 so buffer indices are compile-time.
__global__ __launch_bounds__(256) void qkv_gemm_all(
    const unsigned short* __restrict__ X,
    const unsigned short* __restrict__ Wq,
    const unsigned short* __restrict__ Wk,
    const unsigned short* __restrict__ Wv,
    const float* __restrict__ bq,
    const float* __restrict__ bk,
    const float* __restrict__ bv,
    unsigned short* __restrict__ Qo,
    unsigned short* __restrict__ Ko,
    unsigned short* __restrict__ Vo)
{
    const int id     = blockIdx.x;          // 0..1535
    const int xcd    = id & 7;
    const int within = id >> 3;             // 0..191
    const int z      = within >> 6;         // 0..2
    const int rest   = within & 63;
    const int xb     = rest >> 3;           // n-block 0..7
    const int yb     = xcd * 8 + (rest & 7);// m-block 0..63

    const unsigned short* W = (z == 0) ? Wq : (z == 1) ? Wk : Wv;
    const float* bias = (z == 0) ? bq : (z == 1) ? bk : bv;
    unsigned short* out = (z == 0) ? Qo : (z == 1) ? Ko : Vo;

    const int K = 1024;
    const int t    = threadIdx.x;
    const int lane = t & 63;
    const int wid  = t >> 6;
    const int lo = lane & 15, hi = lane >> 4;
    const int wm = wid >> 1, wn = wid & 1;
    const int m0 = yb * 128;
    const int n0 = xb * 128;

    __shared__ unsigned short As[2][128 * 64];
    __shared__ unsigned short Bs[2][128 * 64];

    const int srowoff = lane >> 3;              // 0..7 within an 8-row group
    const int scol    = lane & 7;               // lds 16B slot

    f32x4 acc[4][4];
#pragma unroll
    for (int i = 0; i < 4; ++i)
#pragma unroll
        for (int j = 0; j < 4; ++j) acc[i][j] = (f32x4){0.f, 0.f, 0.f, 0.f};

#define STAGE_(AS, BS, KOFF)                                                  \
    do {                                                                      \
        _Pragma("unroll") for (int p = 0; p < 4; ++p) {                       \
            const int rowb = p * 32 + wid * 8;                                \
            const int row  = rowb + srowoff;                                  \
            const int c16  = scol ^ (row & 7);                                \
            gload_lds16(&X[(size_t)(m0 + row) * K + (KOFF) + c16 * 8],        \
                        &(AS)[rowb * 64]);                                    \
            gload_lds16(&W[(size_t)(n0 + row) * K + (KOFF) + c16 * 8],        \
                        &(BS)[rowb * 64]);                                    \
        }                                                                     \
    } while (0)

#define COMPUTE_(AS, BS)                                                      \
    do {                                                                      \
        _Pragma("unroll") for (int ks = 0; ks < 2; ++ks) {                    \
            bf16x8 a[4], b[4];                                                \
            _Pragma("unroll") for (int mt = 0; mt < 4; ++mt) {                \
                const int row = wm * 64 + mt * 16 + lo;                       \
                a[mt] = *reinterpret_cast<const bf16x8*>(                     \
                    &(AS)[row * 64 + (((ks * 4 + hi) ^ (lo & 7)) * 8)]);      \
            }                                                                 \
            _Pragma("unroll") for (int nt = 0; nt < 4; ++nt) {                \
                const int row = wn * 64 + nt * 16 + lo;                       \
                b[nt] = *reinterpret_cast<const bf16x8*>(                     \
                    &(BS)[row * 64 + (((ks * 4 + hi) ^ (lo & 7)) * 8)]);      \
            }                                                                 \
            _Pragma("unroll") for (int mt = 0; mt < 4; ++mt)                  \
                _Pragma("unroll") for (int nt = 0; nt < 4; ++nt)              \
                    acc[mt][nt] = __builtin_amdgcn_mfma_f32_16x16x32_bf16(    \
                        a[mt], b[nt], acc[mt][nt], 0, 0, 0);                  \
        }                                                                     \
    } while (0)

    STAGE_(As[0], Bs[0], 0);
    __syncthreads();
#pragma unroll
    for (int k0 = 0; k0 < K; k0 += 128) {
        STAGE_(As[1], Bs[1], k0 + 64);      // issue next while computing cur
        COMPUTE_(As[0], Bs[0]);
        __syncthreads();                     // drains DMA, protects buffers
        if (k0 + 128 < K) STAGE_(As[0], Bs[0], k0 + 128);
        COMPUTE_(As[1], Bs[1]);
        __syncthreads();
    }

#pragma unroll
    for (int nt = 0; nt < 4; ++nt) {
        int n = n0 + wn * 64 + nt * 16 + lo;
        float bv_ = bias[n];
        int h = n >> 6, d = n & 63;
#pragma unroll
        for (int mt = 0; mt < 4; ++mt) {
            int mbase = m0 + wm * 64 + mt * 16 + hi * 4;
            int bb = mbase >> 11;
            int tt = mbase & 2047;
            size_t tilebase = ((size_t)(bb * NH_ + h) * 32 + (tt >> 6)) * 4096;
            if (z == 2) {
                // V fragments: tilebase + ct*1024 + flane*16 + dt*4 (+j)
                ushort4 pk;
                pk.x = f2bf(acc[mt][nt][0] + bv_);
                pk.y = f2bf(acc[mt][nt][1] + bv_);
                pk.z = f2bf(acc[mt][nt][2] + bv_);
                pk.w = f2bf(acc[mt][nt][3] + bv_);
                *reinterpret_cast<ushort4*>(
                    &out[tilebase + (size_t)mt * 1024 + (size_t)(hi * 16 + lo) * 16 + nt * 4]) = pk;
            } else if (z == 1) {
                // K fragments: 4 scalar stores (lo_f = hi*4 + r)
                const int ksd = d >> 5;
                const int hif = (d >> 3) & 3;
                const int jd  = d & 7;
                size_t fragbase = tilebase + (size_t)(mt * 2 + ksd) * 512;
#pragma unroll
                for (int r = 0; r < 4; ++r)
                    out[fragbase + (size_t)(hif * 16 + hi * 4 + r) * 8 + jd] =
                        f2bf(acc[mt][nt][r] + bv_);
            } else {
                size_t base = (size_t)(bb * NH_ + h) * T_;
#pragma unroll
                for (int r = 0; r < 4; ++r)
                    out[(base + tt + r) * HD_ + d] = f2bf(acc[mt][nt][r] + bv_);
            }
        }
    }
#undef STAGE_
#undef COMPUTE_
}

// ---------------------------------------------------------------------------
// Causal flash attention (unchanged from R15): static-exp softmax,
// fragment-order K/V, 4096 blocks, 2-wave kv-split, addition merge.
__global__ __launch_bounds__(128, 2) void attn_fwd15(
    const unsigned short* __restrict__ Q,
    const unsigned short* __restrict__ Kf,
    const unsigned short* __restrict__ Vf,
    const float* __restrict__ amask,
    float* __restrict__ out)
{
    const float SC    = 0.125f * 1.44269504089f;
    const float LOG2E = 1.44269504089f;

    const int lane = threadIdx.x & 63;
    const int w    = threadIdx.x >> 6;          // 0..1
    const int lo = lane & 15, hi = lane >> 4;

    const int bid    = blockIdx.x;
    const int xcd    = bid & 7;
    const int within = bid >> 3;                // 0..511
    const int bh     = xcd * 8 + (within & 7);
    const int u      = 63 - (within >> 3);      // 63..0
    const int b      = bh >> 4;
    const int h      = bh & 15;

    const unsigned short* Qg = Q + (size_t)bh * T_ * HD_;
    const float* am = amask + (size_t)b * T_;
    float* outBase = out + (size_t)b * T_ * H_ + h * HD_;

    __shared__ f32x4 Lo[2][4][64];
    __shared__ float Ll[2][64];

    const int q0   = u * 32;
    const int nt   = (u >> 1) + 1;
    const int half = nt >> 1;
    const int ktBeg = w ? half : 0;
    const int ktEnd = w ? nt : half;

    bf16x8 qf[2][2];
#pragma unroll
    for (int mt = 0; mt < 2; ++mt)
#pragma unroll
        for (int ks = 0; ks < 2; ++ks)
            qf[mt][ks] = *reinterpret_cast<const bf16x8*>(
                &Qg[(size_t)(q0 + mt * 16 + lo) * HD_ + ks * 32 + hi * 8]);

    f32x4 o[2][4];
#pragma unroll
    for (int mt = 0; mt < 2; ++mt)
#pragma unroll
        for (int dt = 0; dt < 4; ++dt) o[mt][dt] = (f32x4){0.f, 0.f, 0.f, 0.f};
    float l_r[2] = {0.f, 0.f};

    const unsigned short* kp = Kf + ((size_t)bh * 32 + ktBeg) * 4096;
    const unsigned short* vp = Vf + ((size_t)bh * 32 + ktBeg) * 4096;
    const float*          ap = am + ktBeg * 64;

    for (int kt = ktBeg; kt < ktEnd; ++kt, kp += 4096, vp += 4096, ap += 64) {
        const int kv0 = kt * 64;

        bf16x8 kf[4][2];
#pragma unroll
        for (int ct = 0; ct < 4; ++ct)
#pragma unroll
            for (int ks = 0; ks < 2; ++ks)
                kf[ct][ks] = *reinterpret_cast<const bf16x8*>(
                    &kp[(ct * 2 + ks) * 512 + lane * 8]);

        short4v vf[4][4];
#pragma unroll
        for (int ct = 0; ct < 4; ++ct) {
            union { ushort8v u8; short4v s4[2]; } va, vb;
            va.u8 = *reinterpret_cast<const ushort8v*>(&vp[ct * 1024 + lane * 16]);
            vb.u8 = *reinterpret_cast<const ushort8v*>(&vp[ct * 1024 + lane * 16 + 8]);
            vf[0][ct] = va.s4[0];
            vf[1][ct] = va.s4[1];
            vf[2][ct] = vb.s4[0];
            vf[3][ct] = vb.s4[1];
        }

        f32x4 amv[4];
#pragma unroll
        for (int ct = 0; ct < 4; ++ct)
            amv[ct] = *reinterpret_cast<const f32x4*>(&ap[ct * 16 + hi * 4]) * LOG2E;

        f32x4 s[2][4];
#pragma unroll
        for (int mt = 0; mt < 2; ++mt)
#pragma unroll
            for (int ct = 0; ct < 4; ++ct) s[mt][ct] = (f32x4){0.f, 0.f, 0.f, 0.f};
#pragma unroll
        for (int ks = 0; ks < 2; ++ks)
#pragma unroll
            for (int ct = 0; ct < 4; ++ct)
#pragma unroll
                for (int mt = 0; mt < 2; ++mt)
                    s[mt][ct] = __builtin_amdgcn_mfma_f32_16x16x32_bf16(
                        kf[ct][ks], qf[mt][ks], s[mt][ct], 0, 0, 0);

        const bool edge = (kv0 + 63 > q0);

        short4v p[2][4];
#pragma unroll
        for (int mt = 0; mt < 2; ++mt) {
            f32x4 rsv = (f32x4){0.f, 0.f, 0.f, 0.f};
#pragma unroll
            for (int ct = 0; ct < 4; ++ct) {
                f32x4 sv;
#pragma unroll
                for (int r = 0; r < 4; ++r)
                    sv[r] = fmaf(s[mt][ct][r], SC, amv[ct][r]);
                if (edge) {
                    const int q = q0 + mt * 16 + lo;
#pragma unroll
                    for (int r = 0; r < 4; ++r)
                        if (kv0 + ct * 16 + hi * 4 + r > q) sv[r] = -INFINITY;
                }
                short4v pk;
#pragma unroll
                for (int r = 0; r < 4; ++r) {
                    float pe = exp2f(sv[r]);      // static exponent
                    rsv[r] += pe;
                    __bf16 hb = (__bf16)pe;
                    pk[r] = __builtin_bit_cast(short, hb);
                }
                p[mt][ct] = pk;
            }
            l_r[mt] += (rsv[0] + rsv[1]) + (rsv[2] + rsv[3]);
        }

#pragma unroll
        for (int ct = 0; ct < 4; ++ct)
#pragma unroll
            for (int mt = 0; mt < 2; ++mt)
#pragma unroll
                for (int dt = 0; dt < 4; ++dt)
                    o[mt][dt] = mfma16x16x16bf16(vf[dt][ct], p[mt][ct], o[mt][dt]);
    }

    if (w == 1) {
#pragma unroll
        for (int mt = 0; mt < 2; ++mt) {
            Ll[mt][lane] = l_r[mt];
#pragma unroll
            for (int dt = 0; dt < 4; ++dt)
                Lo[mt][dt][lane] = o[mt][dt];
        }
    }
    __syncthreads();
    if (w == 0) {
#pragma unroll
        for (int mt = 0; mt < 2; ++mt) {
            float lf = l_r[mt] + Ll[mt][lane];
            lf += __shfl_xor(lf, 16, 64);
            lf += __shfl_xor(lf, 32, 64);
            const float inv = 1.0f / lf;
            const int tq = q0 + mt * 16 + lo;
            float* orow = outBase + (size_t)tq * H_;
#pragma unroll
            for (int dt = 0; dt < 4; ++dt) {
                f32x4 v = (o[mt][dt] + Lo[mt][dt][lane]) * inv;
                *reinterpret_cast<f32x4*>(&orow[dt * 16 + hi * 4]) = v;
            }
        }
    }
}

// ---------------------------------------------------------------------------
extern "C" void kernel_launch(void* const* d_in, const int* in_sizes, int n_in,
                              void* d_out, int out_size, void* d_ws, size_t ws_size,
                              hipStream_t stream) {
    const float* hs    = (const float*)d_in[0];
    const float* amask = (const float*)d_in[1];
    const float* Wq    = (const float*)d_in[2];
    const float* bq    = (const float*)d_in[3];
    const float* Wk    = (const float*)d_in[4];
    const float* bk    = (const float*)d_in[5];
    const float* Wv    = (const float*)d_in[6];
    const float* bv    = (const float*)d_in[7];
    float* out = (float*)d_out;

    unsigned short* Xbf = (unsigned short*)d_ws;
    unsigned short* Wqb = Xbf + (size_t)8192 * 1024;
    unsigned short* Wkb = Wqb + (size_t)1024 * 1024;
    unsigned short* Wvb = Wkb + (size_t)1024 * 1024;
    unsigned short* Qb  = Wvb + (size_t)1024 * 1024;
    unsigned short* Kfb = Qb  + (size_t)B_ * NH_ * T_ * HD_;   // K fragment order
    unsigned short* Vfb = Kfb + (size_t)B_ * NH_ * T_ * HD_;   // V fragment order

    cvt_f32_bf16<<<4096, 256, 0, stream>>>(hs, Xbf, (8192 * 1024) / 8);
    dim3 gw(512, 3);
    cvt_w3<<<gw, 256, 0, stream>>>(Wq, Wk, Wv, Wqb, Wkb, Wvb, (1024 * 1024) / 8);

    qkv_gemm_all<<<1536, 256, 0, stream>>>(Xbf, Wqb, Wkb, Wvb, bq, bk, bv,
                                           Qb, Kfb, Vfb);

    attn_fwd15<<<4096, 128, 0, stream>>>(Qb, Kfb, Vfb, amask, out);
}

// Round 19
// 150.969 us; speedup vs baseline: 1.0970x; 1.0221x over previous
//
#include <hip/hip_runtime.h>
#include <math.h>

// Problem constants
#define B_  4
#define T_  2048
#define H_  1024
#define NH_ 16
#define HD_ 64

typedef __bf16  bf16x8  __attribute__((ext_vector_type(8)));
typedef float   f32x4   __attribute__((ext_vector_type(4)));
typedef unsigned short ushort8v __attribute__((ext_vector_type(8)));
typedef short   short4v __attribute__((ext_vector_type(4)));

__device__ __forceinline__ unsigned short f2bf(float f) {
    unsigned int u = __builtin_bit_cast(unsigned int, f);
    u += 0x7fffu + ((u >> 16) & 1u);
    return (unsigned short)(u >> 16);
}

// 16x16x16 bf16 MFMA (K=16): A/B k=(lane>>4)*4+j
__device__ __forceinline__ f32x4 mfma16x16x16bf16(short4v a, short4v b, f32x4 c) {
#if __has_builtin(__builtin_amdgcn_mfma_f32_16x16x16bf16_1k)
    return __builtin_amdgcn_mfma_f32_16x16x16bf16_1k(a, b, c, 0, 0, 0);
#else
    f32x4 d = c;
    asm volatile("v_mfma_f32_16x16x16_bf16 %0, %1, %2, %0\n\ts_nop 7\n\ts_nop 7"
                 : "+v"(d) : "v"(a), "v"(b));
    return d;
#endif
}

// global -> LDS direct DMA, 16B per lane (dest = wave-uniform base + lane*16)
__device__ __forceinline__ void gload_lds16(const unsigned short* g,
                                            unsigned short* l) {
    __builtin_amdgcn_global_load_lds(
        (const __attribute__((address_space(1))) unsigned int*)g,
        (__attribute__((address_space(3))) unsigned int*)l, 16, 0, 0);
}

#define SBARRIER()   asm volatile("s_barrier" ::: "memory")
#define VMCNT8()     asm volatile("s_waitcnt vmcnt(8)" ::: "memory")
#define VMCNT0()     asm volatile("s_waitcnt vmcnt(0)" ::: "memory")

// ---------------------------------------------------------------------------
__global__ void cvt_f32_bf16(const float* __restrict__ in,
                             unsigned short* __restrict__ out, int n8) {
    int stride = gridDim.x * blockDim.x;
    for (int i = blockIdx.x * blockDim.x + threadIdx.x; i < n8; i += stride) {
        const float4* p = reinterpret_cast<const float4*>(in) + (size_t)i * 2;
        float4 f0 = p[0], f1 = p[1];
        ushort8v o;
        o[0] = f2bf(f0.x); o[1] = f2bf(f0.y); o[2] = f2bf(f0.z); o[3] = f2bf(f0.w);
        o[4] = f2bf(f1.x); o[5] = f2bf(f1.y); o[6] = f2bf(f1.z); o[7] = f2bf(f1.w);
        reinterpret_cast<ushort8v*>(out)[i] = o;
    }
}

// three weight matrices in one launch (grid.y selects)
__global__ void cvt_w3(const float* __restrict__ Wq, const float* __restrict__ Wk,
                       const float* __restrict__ Wv,
                       unsigned short* __restrict__ oq, unsigned short* __restrict__ ok,
                       unsigned short* __restrict__ ov, int n8) {
    const int z = blockIdx.y;
    const float* in = (z == 0) ? Wq : (z == 1) ? Wk : Wv;
    unsigned short* out = (z == 0) ? oq : (z == 1) ? ok : ov;
    int stride = gridDim.x * blockDim.x;
    for (int i = blockIdx.x * blockDim.x + threadIdx.x; i < n8; i += stride) {
        const float4* p = reinterpret_cast<const float4*>(in) + (size_t)i * 2;
        float4 f0 = p[0], f1 = p[1];
        ushort8v o;
        o[0] = f2bf(f0.x); o[1] = f2bf(f0.y); o[2] = f2bf(f0.z); o[3] = f2bf(f0.w);
        o[4] = f2bf(f1.x); o[5] = f2bf(f1.y); o[6] = f2bf(f1.z); o[7] = f2bf(f1.w);
        reinterpret_cast<ushort8v*>(out)[i] = o;
    }
}

// ---------------------------------------------------------------------------
// QKV projection GEMM: XCD-locality decode + double buffer + T4 counted
// vmcnt: the refill's 8 loads stay in flight across the other buffer's
// compute phase; we only ever wait for the oldest 8 (never drain to 0 in
// the main loop). Raw s_barrier (no implicit vmcnt drain).
__global__ __launch_bounds__(256) void qkv_gemm_all(
    const unsigned short* __restrict__ X,
    const unsigned short* __restrict__ Wq,
    const unsigned short* __restrict__ Wk,
    const unsigned short* __restrict__ Wv,
    const float* __restrict__ bq,
    const float* __restrict__ bk,
    const float* __restrict__ bv,
    unsigned short* __restrict__ Qo,
    unsigned short* __restrict__ Ko,
    unsigned short* __restrict__ Vo)
{
    const int id     = blockIdx.x;          // 0..1535
    const int xcd    = id & 7;
    const int within = id >> 3;             // 0..191
    const int z      = within >> 6;         // 0..2
    const int rest   = within & 63;
    const int xb     = rest >> 3;           // n-block 0..7
    const int yb     = xcd * 8 + (rest & 7);// m-block 0..63

    const unsigned short* W = (z == 0) ? Wq : (z == 1) ? Wk : Wv;
    const float* bias = (z == 0) ? bq : (z == 1) ? bk : bv;
    unsigned short* out = (z == 0) ? Qo : (z == 1) ? Ko : Vo;

    const int K = 1024;
    const int t    = threadIdx.x;
    const int lane = t & 63;
    const int wid  = t >> 6;
    const int lo = lane & 15, hi = lane >> 4;
    const int wm = wid >> 1, wn = wid & 1;
    const int m0 = yb * 128;
    const int n0 = xb * 128;

    __shared__ unsigned short As[2][128 * 64];
    __shared__ unsigned short Bs[2][128 * 64];

    const int srowoff = lane >> 3;              // 0..7 within an 8-row group
    const int scol    = lane & 7;               // lds 16B slot

    f32x4 acc[4][4];
#pragma unroll
    for (int i = 0; i < 4; ++i)
#pragma unroll
        for (int j = 0; j < 4; ++j) acc[i][j] = (f32x4){0.f, 0.f, 0.f, 0.f};

#define STAGE_(AS, BS, KOFF)                                                  \
    do {                                                                      \
        _Pragma("unroll") for (int p = 0; p < 4; ++p) {                       \
            const int rowb = p * 32 + wid * 8;                                \
            const int row  = rowb + srowoff;                                  \
            const int c16  = scol ^ (row & 7);                                \
            gload_lds16(&X[(size_t)(m0 + row) * K + (KOFF) + c16 * 8],        \
                        &(AS)[rowb * 64]);                                    \
            gload_lds16(&W[(size_t)(n0 + row) * K + (KOFF) + c16 * 8],        \
                        &(BS)[rowb * 64]);                                    \
        }                                                                     \
    } while (0)

#define COMPUTE_(AS, BS)                                                      \
    do {                                                                      \
        _Pragma("unroll") for (int ks = 0; ks < 2; ++ks) {                    \
            bf16x8 a[4], b[4];                                                \
            _Pragma("unroll") for (int mt = 0; mt < 4; ++mt) {                \
                const int row = wm * 64 + mt * 16 + lo;                       \
                a[mt] = *reinterpret_cast<const bf16x8*>(                     \
                    &(AS)[row * 64 + (((ks * 4 + hi) ^ (lo & 7)) * 8)]);      \
            }                                                                 \
            _Pragma("unroll") for (int nt = 0; nt < 4; ++nt) {                \
                const int row = wn * 64 + nt * 16 + lo;                       \
                b[nt] = *reinterpret_cast<const bf16x8*>(                     \
                    &(BS)[row * 64 + (((ks * 4 + hi) ^ (lo & 7)) * 8)]);      \
            }                                                                 \
            _Pragma("unroll") for (int mt = 0; mt < 4; ++mt)                  \
                _Pragma("unroll") for (int nt = 0; nt < 4; ++nt)              \
                    acc[mt][nt] = __builtin_amdgcn_mfma_f32_16x16x32_bf16(    \
                        a[mt], b[nt], acc[mt][nt], 0, 0, 0);                  \
        }                                                                     \
    } while (0)

    // prologue: fill both buffers; wait only for b0 (b1 stays in flight)
    STAGE_(As[0], Bs[0], 0);
    STAGE_(As[1], Bs[1], 64);
    VMCNT8();
    SBARRIER();

#pragma unroll
    for (int k0 = 0; k0 < K; k0 += 128) {
        // b0 (k = k0) ready; b1 (k = k0+64) in flight
        COMPUTE_(As[0], Bs[0]);
        SBARRIER();                              // all waves done reading b0
        if (k0 + 128 < K) {
            STAGE_(As[0], Bs[0], k0 + 128);      // refill b0 (8 loads)
            VMCNT8();                            // wait oldest 8 = b1's
        } else {
            VMCNT0();
        }
        SBARRIER();                              // b1 ready block-wide
        COMPUTE_(As[1], Bs[1]);
        SBARRIER();                              // all waves done reading b1
        if (k0 + 192 < K) {
            STAGE_(As[1], Bs[1], k0 + 192);      // refill b1
            VMCNT8();                            // wait oldest 8 = b0-refill
        } else {
            VMCNT0();
        }
        SBARRIER();                              // b0-refill ready block-wide
    }

#pragma unroll
    for (int nt = 0; nt < 4; ++nt) {
        int n = n0 + wn * 64 + nt * 16 + lo;
        float bv_ = bias[n];
        int h = n >> 6, d = n & 63;
#pragma unroll
        for (int mt = 0; mt < 4; ++mt) {
            int mbase = m0 + wm * 64 + mt * 16 + hi * 4;
            int bb = mbase >> 11;
            int tt = mbase & 2047;
            size_t tilebase = ((size_t)(bb * NH_ + h) * 32 + (tt >> 6)) * 4096;
            if (z == 2) {
                // V fragments: tilebase + ct*1024 + flane*16 + dt*4 (+j)
                ushort4 pk;
                pk.x = f2bf(acc[mt][nt][0] + bv_);
                pk.y = f2bf(acc[mt][nt][1] + bv_);
                pk.z = f2bf(acc[mt][nt][2] + bv_);
                pk.w = f2bf(acc[mt][nt][3] + bv_);
                *reinterpret_cast<ushort4*>(
                    &out[tilebase + (size_t)mt * 1024 + (size_t)(hi * 16 + lo) * 16 + nt * 4]) = pk;
            } else if (z == 1) {
                // K fragments: 4 scalar stores (lo_f = hi*4 + r)
                const int ksd = d >> 5;
                const int hif = (d >> 3) & 3;
                const int jd  = d & 7;
                size_t fragbase = tilebase + (size_t)(mt * 2 + ksd) * 512;
#pragma unroll
                for (int r = 0; r < 4; ++r)
                    out[fragbase + (size_t)(hif * 16 + hi * 4 + r) * 8 + jd] =
                        f2bf(acc[mt][nt][r] + bv_);
            } else {
                size_t base = (size_t)(bb * NH_ + h) * T_;
#pragma unroll
                for (int r = 0; r < 4; ++r)
                    out[(base + tt + r) * HD_ + d] = f2bf(acc[mt][nt][r] + bv_);
            }
        }
    }
#undef STAGE_
#undef COMPUTE_
}

// ---------------------------------------------------------------------------
// Causal flash attention (unchanged from R15): static-exp softmax,
// fragment-order K/V, 4096 blocks, 2-wave kv-split, addition merge.
__global__ __launch_bounds__(128, 2) void attn_fwd15(
    const unsigned short* __restrict__ Q,
    const unsigned short* __restrict__ Kf,
    const unsigned short* __restrict__ Vf,
    const float* __restrict__ amask,
    float* __restrict__ out)
{
    const float SC    = 0.125f * 1.44269504089f;
    const float LOG2E = 1.44269504089f;

    const int lane = threadIdx.x & 63;
    const int w    = threadIdx.x >> 6;          // 0..1
    const int lo = lane & 15, hi = lane >> 4;

    const int bid    = blockIdx.x;
    const int xcd    = bid & 7;
    const int within = bid >> 3;                // 0..511
    const int bh     = xcd * 8 + (within & 7);
    const int u      = 63 - (within >> 3);      // 63..0
    const int b      = bh >> 4;
    const int h      = bh & 15;

    const unsigned short* Qg = Q + (size_t)bh * T_ * HD_;
    const float* am = amask + (size_t)b * T_;
    float* outBase = out + (size_t)b * T_ * H_ + h * HD_;

    __shared__ f32x4 Lo[2][4][64];
    __shared__ float Ll[2][64];

    const int q0   = u * 32;
    const int nt   = (u >> 1) + 1;
    const int half = nt >> 1;
    const int ktBeg = w ? half : 0;
    const int ktEnd = w ? nt : half;

    bf16x8 qf[2][2];
#pragma unroll
    for (int mt = 0; mt < 2; ++mt)
#pragma unroll
        for (int ks = 0; ks < 2; ++ks)
            qf[mt][ks] = *reinterpret_cast<const bf16x8*>(
                &Qg[(size_t)(q0 + mt * 16 + lo) * HD_ + ks * 32 + hi * 8]);

    f32x4 o[2][4];
#pragma unroll
    for (int mt = 0; mt < 2; ++mt)
#pragma unroll
        for (int dt = 0; dt < 4; ++dt) o[mt][dt] = (f32x4){0.f, 0.f, 0.f, 0.f};
    float l_r[2] = {0.f, 0.f};

    const unsigned short* kp = Kf + ((size_t)bh * 32 + ktBeg) * 4096;
    const unsigned short* vp = Vf + ((size_t)bh * 32 + ktBeg) * 4096;
    const float*          ap = am + ktBeg * 64;

    for (int kt = ktBeg; kt < ktEnd; ++kt, kp += 4096, vp += 4096, ap += 64) {
        const int kv0 = kt * 64;

        bf16x8 kf[4][2];
#pragma unroll
        for (int ct = 0; ct < 4; ++ct)
#pragma unroll
            for (int ks = 0; ks < 2; ++ks)
                kf[ct][ks] = *reinterpret_cast<const bf16x8*>(
                    &kp[(ct * 2 + ks) * 512 + lane * 8]);

        short4v vf[4][4];
#pragma unroll
        for (int ct = 0; ct < 4; ++ct) {
            union { ushort8v u8; short4v s4[2]; } va, vb;
            va.u8 = *reinterpret_cast<const ushort8v*>(&vp[ct * 1024 + lane * 16]);
            vb.u8 = *reinterpret_cast<const ushort8v*>(&vp[ct * 1024 + lane * 16 + 8]);
            vf[0][ct] = va.s4[0];
            vf[1][ct] = va.s4[1];
            vf[2][ct] = vb.s4[0];
            vf[3][ct] = vb.s4[1];
        }

        f32x4 amv[4];
#pragma unroll
        for (int ct = 0; ct < 4; ++ct)
            amv[ct] = *reinterpret_cast<const f32x4*>(&ap[ct * 16 + hi * 4]) * LOG2E;

        f32x4 s[2][4];
#pragma unroll
        for (int mt = 0; mt < 2; ++mt)
#pragma unroll
            for (int ct = 0; ct < 4; ++ct) s[mt][ct] = (f32x4){0.f, 0.f, 0.f, 0.f};
#pragma unroll
        for (int ks = 0; ks < 2; ++ks)
#pragma unroll
            for (int ct = 0; ct < 4; ++ct)
#pragma unroll
                for (int mt = 0; mt < 2; ++mt)
                    s[mt][ct] = __builtin_amdgcn_mfma_f32_16x16x32_bf16(
                        kf[ct][ks], qf[mt][ks], s[mt][ct], 0, 0, 0);

        const bool edge = (kv0 + 63 > q0);

        short4v p[2][4];
#pragma unroll
        for (int mt = 0; mt < 2; ++mt) {
            f32x4 rsv = (f32x4){0.f, 0.f, 0.f, 0.f};
#pragma unroll
            for (int ct = 0; ct < 4; ++ct) {
                f32x4 sv;
#pragma unroll
                for (int r = 0; r < 4; ++r)
                    sv[r] = fmaf(s[mt][ct][r], SC, amv[ct][r]);
                if (edge) {
                    const int q = q0 + mt * 16 + lo;
#pragma unroll
                    for (int r = 0; r < 4; ++r)
                        if (kv0 + ct * 16 + hi * 4 + r > q) sv[r] = -INFINITY;
                }
                short4v pk;
#pragma unroll
                for (int r = 0; r < 4; ++r) {
                    float pe = exp2f(sv[r]);      // static exponent
                    rsv[r] += pe;
                    __bf16 hb = (__bf16)pe;
                    pk[r] = __builtin_bit_cast(short, hb);
                }
                p[mt][ct] = pk;
            }
            l_r[mt] += (rsv[0] + rsv[1]) + (rsv[2] + rsv[3]);
        }

#pragma unroll
        for (int ct = 0; ct < 4; ++ct)
#pragma unroll
            for (int mt = 0; mt < 2; ++mt)
#pragma unroll
                for (int dt = 0; dt < 4; ++dt)
                    o[mt][dt] = mfma16x16x16bf16(vf[dt][ct], p[mt][ct], o[mt][dt]);
    }

    if (w == 1) {
#pragma unroll
        for (int mt = 0; mt < 2; ++mt) {
            Ll[mt][lane] = l_r[mt];
#pragma unroll
            for (int dt = 0; dt < 4; ++dt)
                Lo[mt][dt][lane] = o[mt][dt];
        }
    }
    __syncthreads();
    if (w == 0) {
#pragma unroll
        for (int mt = 0; mt < 2; ++mt) {
            float lf = l_r[mt] + Ll[mt][lane];
            lf += __shfl_xor(lf, 16, 64);
            lf += __shfl_xor(lf, 32, 64);
            const float inv = 1.0f / lf;
            const int tq = q0 + mt * 16 + lo;
            float* orow = outBase + (size_t)tq * H_;
#pragma unroll
            for (int dt = 0; dt < 4; ++dt) {
                f32x4 v = (o[mt][dt] + Lo[mt][dt][lane]) * inv;
                *reinterpret_cast<f32x4*>(&orow[dt * 16 + hi * 4]) = v;
            }
        }
    }
}

// ---------------------------------------------------------------------------
extern "C" void kernel_launch(void* const* d_in, const int* in_sizes, int n_in,
                              void* d_out, int out_size, void* d_ws, size_t ws_size,
                              hipStream_t stream) {
    const float* hs    = (const float*)d_in[0];
    const float* amask = (const float*)d_in[1];
    const float* Wq    = (const float*)d_in[2];
    const float* bq    = (const float*)d_in[3];
    const float* Wk    = (const float*)d_in[4];
    const float* bk    = (const float*)d_in[5];
    const float* Wv    = (const float*)d_in[6];
    const float* bv    = (const float*)d_in[7];
    float* out = (float*)d_out;

    unsigned short* Xbf = (unsigned short*)d_ws;
    unsigned short* Wqb = Xbf + (size_t)8192 * 1024;
    unsigned short* Wkb = Wqb + (size_t)1024 * 1024;
    unsigned short* Wvb = Wkb + (size_t)1024 * 1024;
    unsigned short* Qb  = Wvb + (size_t)1024 * 1024;
    unsigned short* Kfb = Qb  + (size_t)B_ * NH_ * T_ * HD_;   // K fragment order
    unsigned short* Vfb = Kfb + (size_t)B_ * NH_ * T_ * HD_;   // V fragment order

    cvt_f32_bf16<<<4096, 256, 0, stream>>>(hs, Xbf, (8192 * 1024) / 8);
    dim3 gw(512, 3);
    cvt_w3<<<gw, 256, 0, stream>>>(Wq, Wk, Wv, Wqb, Wkb, Wvb, (1024 * 1024) / 8);

    qkv_gemm_all<<<1536, 256, 0, stream>>>(Xbf, Wqb, Wkb, Wvb, bq, bk, bv,
                                           Qb, Kfb, Vfb);

    attn_fwd15<<<4096, 128, 0, stream>>>(Qb, Kfb, Vfb, amask, out);
}